// Round 1
// baseline (49.206 us; speedup 1.0000x reference)
//
#include <hip/hip_runtime.h>
#include <hip/hip_bf16.h>

typedef __attribute__((ext_vector_type(4))) float f32x4;
typedef __attribute__((ext_vector_type(8))) __bf16 bf16x8;

#define B_DIM 16
#define L_DIM 1024
#define D_DIM 256

// ---------------------------------------------------------------------------
// Kernel 1: row norms.  nrm[0..16383] = ||s1 rows||^2, nrm[16384..32767] = ||s2 rows||^2
// One wave per row (64 lanes x float4 = 256 elements).
// ---------------------------------------------------------------------------
__global__ __launch_bounds__(256) void norms_kernel(const float* __restrict__ s1,
                                                    const float* __restrict__ s2,
                                                    float* __restrict__ nrm) {
    int w = threadIdx.x >> 6, l = threadIdx.x & 63;
    int row = (blockIdx.x << 2) + w;  // 0 .. 32767
    const float* src = (row < B_DIM * L_DIM)
                           ? (s1 + (size_t)row * D_DIM)
                           : (s2 + (size_t)(row - B_DIM * L_DIM) * D_DIM);
    float4 v = reinterpret_cast<const float4*>(src)[l];
    float s = v.x * v.x + v.y * v.y + v.z * v.z + v.w * v.w;
#pragma unroll
    for (int o = 32; o > 0; o >>= 1) s += __shfl_xor(s, o, 64);
    if (l == 0) nrm[row] = s;
}

// ---------------------------------------------------------------------------
// Kernel 2: batched GEMM-BT (xy = s1 . s2^T per batch) with fused fp32->bf16
// conversion in reg-staging, 128x128 tile, BK=32, 4 waves, 16x16x32 bf16 MFMA,
// epilogue out = 1/(1+sqrt(max(x2+y2-2xy,0))).
// ---------------------------------------------------------------------------
__global__ __launch_bounds__(256) void dist_gemm_kernel(const float* __restrict__ s1,
                                                        const float* __restrict__ s2,
                                                        const float* __restrict__ nrm,
                                                        float* __restrict__ out) {
    __shared__ __bf16 Alds[2][128 * 32];
    __shared__ __bf16 Blds[2][128 * 32];

    const int t = threadIdx.x;
    const int p = blockIdx.x;
    // XCD-aware swizzle: physical block p lands on XCD p%8; remap so each XCD
    // owns 128 consecutive logical tiles = 2 full batches (input fp32 L2-hits).
    const int d = ((p & 7) << 7) + (p >> 3);  // bijective for 1024 blocks
    const int batch = d >> 6;
    const int tile = d & 63;
    const int row0 = (tile >> 3) << 7;
    const int col0 = (tile & 7) << 7;

    const float* Ag = s1 + ((size_t)batch * L_DIM + row0) * D_DIM;
    const float* Bg = s2 + ((size_t)batch * L_DIM + col0) * D_DIM;

    // staging map: thread t covers row sr (+64 per pass), 8 consecutive k at sc
    const int sr = t >> 2;
    const int sc = (t & 3) << 3;

    const int l = t & 63, w = t >> 6;
    const int wr = w >> 1, wc = w & 1;   // wave -> 64x64 quadrant
    const int lr = l & 15;               // frag row (A) / col (B,C)
    const int lk = (l >> 4) << 3;        // frag k-offset (elements)

    f32x4 acc[4][4] = {};

    auto stage = [&](int buf, int k0) {
#pragma unroll
        for (int pass = 0; pass < 2; ++pass) {
            const int r = sr + (pass << 6);
            const float4* sa = reinterpret_cast<const float4*>(Ag + (size_t)r * D_DIM + k0 + sc);
            float4 a0 = sa[0], a1 = sa[1];
            const float4* sb = reinterpret_cast<const float4*>(Bg + (size_t)r * D_DIM + k0 + sc);
            float4 b0 = sb[0], b1 = sb[1];
            bf16x8 av, bv;
            av[0] = (__bf16)a0.x; av[1] = (__bf16)a0.y; av[2] = (__bf16)a0.z; av[3] = (__bf16)a0.w;
            av[4] = (__bf16)a1.x; av[5] = (__bf16)a1.y; av[6] = (__bf16)a1.z; av[7] = (__bf16)a1.w;
            bv[0] = (__bf16)b0.x; bv[1] = (__bf16)b0.y; bv[2] = (__bf16)b0.z; bv[3] = (__bf16)b0.w;
            bv[4] = (__bf16)b1.x; bv[5] = (__bf16)b1.y; bv[6] = (__bf16)b1.z; bv[7] = (__bf16)b1.w;
            *reinterpret_cast<bf16x8*>(&Alds[buf][(r << 5) + sc]) = av;
            *reinterpret_cast<bf16x8*>(&Blds[buf][(r << 5) + sc]) = bv;
        }
    };

    stage(0, 0);
    __syncthreads();
    int cur = 0;
    for (int kt = 0; kt < 8; ++kt) {
        if (kt < 7) stage(cur ^ 1, (kt + 1) << 5);
        bf16x8 aF[4], bF[4];
#pragma unroll
        for (int m = 0; m < 4; ++m)
            aF[m] = *reinterpret_cast<const bf16x8*>(
                &Alds[cur][(((wr << 6) + (m << 4) + lr) << 5) + lk]);
#pragma unroll
        for (int n = 0; n < 4; ++n)
            bF[n] = *reinterpret_cast<const bf16x8*>(
                &Blds[cur][(((wc << 6) + (n << 4) + lr) << 5) + lk]);
#pragma unroll
        for (int m = 0; m < 4; ++m)
#pragma unroll
            for (int n = 0; n < 4; ++n)
                acc[m][n] = __builtin_amdgcn_mfma_f32_16x16x32_bf16(aF[m], bF[n], acc[m][n], 0, 0, 0);
        __syncthreads();
        cur ^= 1;
    }

    // epilogue
    const float* x2 = nrm + batch * L_DIM;
    const float* y2 = nrm + B_DIM * L_DIM + batch * L_DIM;
    float* outb = out + (size_t)batch * L_DIM * L_DIM;
    const int rbase = row0 + (wr << 6) + ((l >> 4) << 2);
    const int cbase = col0 + (wc << 6) + lr;
#pragma unroll
    for (int n = 0; n < 4; ++n) {
        const int col = cbase + (n << 4);
        const float y2v = y2[col];
#pragma unroll
        for (int m = 0; m < 4; ++m) {
            const int rowf = rbase + (m << 4);
#pragma unroll
            for (int r = 0; r < 4; ++r) {
                const int row = rowf + r;
                float sq = x2[row] + y2v - 2.0f * acc[m][n][r];
                sq = fmaxf(sq, 0.0f);
                outb[(size_t)row * L_DIM + col] = 1.0f / (1.0f + sqrtf(sq));
            }
        }
    }
}

extern "C" void kernel_launch(void* const* d_in, const int* in_sizes, int n_in,
                              void* d_out, int out_size, void* d_ws, size_t ws_size,
                              hipStream_t stream) {
    (void)in_sizes; (void)n_in; (void)out_size; (void)ws_size;
    const float* s1 = (const float*)d_in[1];
    const float* s2 = (const float*)d_in[2];
    float* nrm = (float*)d_ws;   // 32768 floats = 128 KB
    float* out = (float*)d_out;

    norms_kernel<<<8192, 256, 0, stream>>>(s1, s2, nrm);
    dist_gemm_kernel<<<1024, 256, 0, stream>>>(s1, s2, nrm, out);
}

// Round 2
// 43.804 us; speedup vs baseline: 1.1233x; 1.1233x over previous
//
#include <hip/hip_runtime.h>
#include <hip/hip_bf16.h>

typedef __attribute__((ext_vector_type(4))) float f32x4;
typedef __attribute__((ext_vector_type(8))) __bf16 bf16x8;
typedef __attribute__((ext_vector_type(4))) __bf16 bf16x4;

#define B_DIM 16
#define L_DIM 1024
#define D_DIM 256

#define GLOAD_LDS16(g, lptr)                                          \
    __builtin_amdgcn_global_load_lds(                                 \
        (const __attribute__((address_space(1))) void*)(g),           \
        (__attribute__((address_space(3))) void*)(lptr), 16, 0, 0)

// ---------------------------------------------------------------------------
// Prep: row norms + fp32->bf16 conversion in one pass.
// nrm[0..16383] = ||s1 rows||^2, nrm[16384..32767] = ||s2 rows||^2.
// One wave per row (64 lanes x float4 = 256 elements).
// ---------------------------------------------------------------------------
__global__ __launch_bounds__(256) void prep_kernel(const float* __restrict__ s1,
                                                   const float* __restrict__ s2,
                                                   float* __restrict__ nrm,
                                                   __hip_bfloat16* __restrict__ s1b,
                                                   __hip_bfloat16* __restrict__ s2b) {
    int w = threadIdx.x >> 6, l = threadIdx.x & 63;
    int row = (blockIdx.x << 2) + w;       // 0 .. 32767
    int second = row >> 14;                // rows >= 16384 are s2
    int r = row & 16383;
    const float* src = (second ? s2 : s1) + (size_t)r * D_DIM;
    __hip_bfloat16* dst = (second ? s2b : s1b) + (size_t)r * D_DIM;
    float4 v = reinterpret_cast<const float4*>(src)[l];
    float s = v.x * v.x + v.y * v.y + v.z * v.z + v.w * v.w;
    bf16x4 bv;
    bv[0] = (__bf16)v.x; bv[1] = (__bf16)v.y; bv[2] = (__bf16)v.z; bv[3] = (__bf16)v.w;
    *reinterpret_cast<bf16x4*>(dst + l * 4) = bv;
#pragma unroll
    for (int o = 32; o > 0; o >>= 1) s += __shfl_xor(s, o, 64);
    if (l == 0) nrm[row] = s;
}

// ---------------------------------------------------------------------------
// Main GEMM: bf16 inputs, global_load_lds(16B) staging, XOR-swizzled LDS,
// 128x128 tile, BK=32, 4 waves, 16x16x32 bf16 MFMA,
// epilogue out = 1/(1+sqrt(max(x2+y2-2xy,0))).
// Swizzle: 16B slot index ^= (row>>1)&3  (row stride is 64B = 4 slots).
// Applied on global SOURCE addr during staging (LDS dest stays linear) and on
// the ds_read address. Quarter-wave then hits all 8 bank-groups 2x = free.
// ---------------------------------------------------------------------------
__global__ __launch_bounds__(256) void dist_gemm_bf16_kernel(const __hip_bfloat16* __restrict__ s1b,
                                                             const __hip_bfloat16* __restrict__ s2b,
                                                             const float* __restrict__ nrm,
                                                             float* __restrict__ out) {
    __shared__ __bf16 Alds[2][128 * 32];
    __shared__ __bf16 Blds[2][128 * 32];

    const int t = threadIdx.x;
    const int p = blockIdx.x;
    // XCD-aware swizzle: each XCD owns 128 consecutive logical tiles = 2 batches.
    const int d = ((p & 7) << 7) + (p >> 3);  // bijective for 1024 blocks
    const int batch = d >> 6;
    const int tile = d & 63;
    const int row0 = (tile >> 3) << 7;
    const int col0 = (tile & 7) << 7;

    const __hip_bfloat16* Ag = s1b + ((size_t)batch * L_DIM + row0) * D_DIM;
    const __hip_bfloat16* Bg = s2b + ((size_t)batch * L_DIM + col0) * D_DIM;

    const int l = t & 63, w = t >> 6;
    const int wr = w >> 1, wc = w & 1;   // wave -> 64x64 quadrant
    const int lr = l & 15;               // frag row (A) / col (B,C)
    const int lq = l >> 4;               // quarter = base 16B slot

    // staging geometry: wave w, call i covers segment s = w*2+i = rows s*16..+15.
    // lane l -> row s*16 + (l>>2), slot l&3; content slot = (l&3) ^ ((l>>3)&3).
    const int srow_in_seg = l >> 2;
    const int sslot = (l & 3) ^ ((l >> 3) & 3);

    f32x4 acc[4][4] = {};

    auto stage = [&](int buf, int k0) {
#pragma unroll
        for (int i = 0; i < 2; ++i) {
            const int s = (w << 1) | i;
            const int rl = (s << 4) + srow_in_seg;
            const __hip_bfloat16* ga = Ag + rl * D_DIM + k0 + sslot * 8;
            const __hip_bfloat16* gb = Bg + rl * D_DIM + k0 + sslot * 8;
            GLOAD_LDS16(ga, &Alds[buf][s << 9]);
            GLOAD_LDS16(gb, &Blds[buf][s << 9]);
        }
    };

    stage(0, 0);
    __syncthreads();
    int cur = 0;
#pragma unroll
    for (int kt = 0; kt < 8; ++kt) {
        if (kt < 7) stage(cur ^ 1, (kt + 1) << 5);
        bf16x8 aF[4], bF[4];
#pragma unroll
        for (int m = 0; m < 4; ++m) {
            const int row = (wr << 6) + (m << 4) + lr;
            const int sl = lq ^ ((row >> 1) & 3);
            aF[m] = *reinterpret_cast<const bf16x8*>(&Alds[cur][(row << 5) + (sl << 3)]);
        }
#pragma unroll
        for (int n = 0; n < 4; ++n) {
            const int row = (wc << 6) + (n << 4) + lr;
            const int sl = lq ^ ((row >> 1) & 3);
            bF[n] = *reinterpret_cast<const bf16x8*>(&Blds[cur][(row << 5) + (sl << 3)]);
        }
#pragma unroll
        for (int m = 0; m < 4; ++m)
#pragma unroll
            for (int n = 0; n < 4; ++n)
                acc[m][n] = __builtin_amdgcn_mfma_f32_16x16x32_bf16(aF[m], bF[n], acc[m][n], 0, 0, 0);
        __syncthreads();
        cur ^= 1;
    }

    // epilogue
    const float* x2 = nrm + batch * L_DIM;
    const float* y2 = nrm + B_DIM * L_DIM + batch * L_DIM;
    float* outb = out + (size_t)batch * L_DIM * L_DIM;
    const int rbase = row0 + (wr << 6) + (lq << 2);
    const int cbase = col0 + (wc << 6) + lr;
#pragma unroll
    for (int n = 0; n < 4; ++n) {
        const int col = cbase + (n << 4);
        const float y2v = y2[col];
#pragma unroll
        for (int m = 0; m < 4; ++m) {
            const int rowf = rbase + (m << 4);
#pragma unroll
            for (int r = 0; r < 4; ++r) {
                const int row = rowf + r;
                float sq = x2[row] + y2v - 2.0f * acc[m][n][r];
                sq = fmaxf(sq, 0.0f);
                outb[(size_t)row * L_DIM + col] = 1.0f / (1.0f + sqrtf(sq));
            }
        }
    }
}

// ---------------------------------------------------------------------------
// Fallback path (round-1 kernels) for the case ws_size < needed.
// ---------------------------------------------------------------------------
__global__ __launch_bounds__(256) void norms_kernel(const float* __restrict__ s1,
                                                    const float* __restrict__ s2,
                                                    float* __restrict__ nrm) {
    int w = threadIdx.x >> 6, l = threadIdx.x & 63;
    int row = (blockIdx.x << 2) + w;
    const float* src = (row < B_DIM * L_DIM)
                           ? (s1 + (size_t)row * D_DIM)
                           : (s2 + (size_t)(row - B_DIM * L_DIM) * D_DIM);
    float4 v = reinterpret_cast<const float4*>(src)[l];
    float s = v.x * v.x + v.y * v.y + v.z * v.z + v.w * v.w;
#pragma unroll
    for (int o = 32; o > 0; o >>= 1) s += __shfl_xor(s, o, 64);
    if (l == 0) nrm[row] = s;
}

__global__ __launch_bounds__(256) void dist_gemm_kernel(const float* __restrict__ s1,
                                                        const float* __restrict__ s2,
                                                        const float* __restrict__ nrm,
                                                        float* __restrict__ out) {
    __shared__ __bf16 Alds[2][128 * 32];
    __shared__ __bf16 Blds[2][128 * 32];

    const int t = threadIdx.x;
    const int p = blockIdx.x;
    const int d = ((p & 7) << 7) + (p >> 3);
    const int batch = d >> 6;
    const int tile = d & 63;
    const int row0 = (tile >> 3) << 7;
    const int col0 = (tile & 7) << 7;

    const float* Ag = s1 + ((size_t)batch * L_DIM + row0) * D_DIM;
    const float* Bg = s2 + ((size_t)batch * L_DIM + col0) * D_DIM;

    const int sr = t >> 2;
    const int sc = (t & 3) << 3;

    const int l = t & 63, w = t >> 6;
    const int wr = w >> 1, wc = w & 1;
    const int lr = l & 15;
    const int lk = (l >> 4) << 3;

    f32x4 acc[4][4] = {};

    auto stage = [&](int buf, int k0) {
#pragma unroll
        for (int pass = 0; pass < 2; ++pass) {
            const int r = sr + (pass << 6);
            const float4* sa = reinterpret_cast<const float4*>(Ag + (size_t)r * D_DIM + k0 + sc);
            float4 a0 = sa[0], a1 = sa[1];
            const float4* sb = reinterpret_cast<const float4*>(Bg + (size_t)r * D_DIM + k0 + sc);
            float4 b0 = sb[0], b1 = sb[1];
            bf16x8 av, bv;
            av[0] = (__bf16)a0.x; av[1] = (__bf16)a0.y; av[2] = (__bf16)a0.z; av[3] = (__bf16)a0.w;
            av[4] = (__bf16)a1.x; av[5] = (__bf16)a1.y; av[6] = (__bf16)a1.z; av[7] = (__bf16)a1.w;
            bv[0] = (__bf16)b0.x; bv[1] = (__bf16)b0.y; bv[2] = (__bf16)b0.z; bv[3] = (__bf16)b0.w;
            bv[4] = (__bf16)b1.x; bv[5] = (__bf16)b1.y; bv[6] = (__bf16)b1.z; bv[7] = (__bf16)b1.w;
            *reinterpret_cast<bf16x8*>(&Alds[buf][(r << 5) + sc]) = av;
            *reinterpret_cast<bf16x8*>(&Blds[buf][(r << 5) + sc]) = bv;
        }
    };

    stage(0, 0);
    __syncthreads();
    int cur = 0;
    for (int kt = 0; kt < 8; ++kt) {
        if (kt < 7) stage(cur ^ 1, (kt + 1) << 5);
        bf16x8 aF[4], bF[4];
#pragma unroll
        for (int m = 0; m < 4; ++m)
            aF[m] = *reinterpret_cast<const bf16x8*>(
                &Alds[cur][(((wr << 6) + (m << 4) + lr) << 5) + lk]);
#pragma unroll
        for (int n = 0; n < 4; ++n)
            bF[n] = *reinterpret_cast<const bf16x8*>(
                &Blds[cur][(((wc << 6) + (n << 4) + lr) << 5) + lk]);
#pragma unroll
        for (int m = 0; m < 4; ++m)
#pragma unroll
            for (int n = 0; n < 4; ++n)
                acc[m][n] = __builtin_amdgcn_mfma_f32_16x16x32_bf16(aF[m], bF[n], acc[m][n], 0, 0, 0);
        __syncthreads();
        cur ^= 1;
    }

    const float* x2 = nrm + batch * L_DIM;
    const float* y2 = nrm + B_DIM * L_DIM + batch * L_DIM;
    float* outb = out + (size_t)batch * L_DIM * L_DIM;
    const int rbase = row0 + (wr << 6) + ((l >> 4) << 2);
    const int cbase = col0 + (wc << 6) + lr;
#pragma unroll
    for (int n = 0; n < 4; ++n) {
        const int col = cbase + (n << 4);
        const float y2v = y2[col];
#pragma unroll
        for (int m = 0; m < 4; ++m) {
            const int rowf = rbase + (m << 4);
#pragma unroll
            for (int r = 0; r < 4; ++r) {
                const int row = rowf + r;
                float sq = x2[row] + y2v - 2.0f * acc[m][n][r];
                sq = fmaxf(sq, 0.0f);
                outb[(size_t)row * L_DIM + col] = 1.0f / (1.0f + sqrtf(sq));
            }
        }
    }
}

extern "C" void kernel_launch(void* const* d_in, const int* in_sizes, int n_in,
                              void* d_out, int out_size, void* d_ws, size_t ws_size,
                              hipStream_t stream) {
    (void)in_sizes; (void)n_in; (void)out_size;
    const float* s1 = (const float*)d_in[1];
    const float* s2 = (const float*)d_in[2];
    float* out = (float*)d_out;

    const size_t NRM_BYTES = 2u * B_DIM * L_DIM * sizeof(float);          // 128 KB
    const size_t BF_BYTES = (size_t)B_DIM * L_DIM * D_DIM * sizeof(__hip_bfloat16);  // 8 MB each
    const size_t NEED = NRM_BYTES + 2 * BF_BYTES;                          // ~16.9 MB

    float* nrm = (float*)d_ws;
    if (ws_size >= NEED) {
        __hip_bfloat16* s1b = (__hip_bfloat16*)((char*)d_ws + NRM_BYTES);
        __hip_bfloat16* s2b = (__hip_bfloat16*)((char*)d_ws + NRM_BYTES + BF_BYTES);
        prep_kernel<<<8192, 256, 0, stream>>>(s1, s2, nrm, s1b, s2b);
        dist_gemm_bf16_kernel<<<1024, 256, 0, stream>>>(s1b, s2b, nrm, out);
    } else {
        norms_kernel<<<8192, 256, 0, stream>>>(s1, s2, nrm);
        dist_gemm_kernel<<<1024, 256, 0, stream>>>(s1, s2, nrm, out);
    }
}

// Round 3
// 40.906 us; speedup vs baseline: 1.2029x; 1.0708x over previous
//
#include <hip/hip_runtime.h>
#include <hip/hip_bf16.h>

typedef __attribute__((ext_vector_type(4))) float f32x4;
typedef __attribute__((ext_vector_type(8))) __bf16 bf16x8;
typedef __attribute__((ext_vector_type(4))) __bf16 bf16x4;

#define B_DIM 16
#define L_DIM 1024
#define D_DIM 256

#define GLOAD_LDS16(g, lptr)                                          \
    __builtin_amdgcn_global_load_lds(                                 \
        (const __attribute__((address_space(1))) void*)(g),           \
        (__attribute__((address_space(3))) void*)(lptr), 16, 0, 0)

// ---------------------------------------------------------------------------
// Prep: row norms + fp32->bf16 conversion in one pass.
// nrm[0..16383] = ||s1 rows||^2, nrm[16384..32767] = ||s2 rows||^2.
// 16 rows per block (4 per wave), 2048 blocks. Lane l covers elements 4l..4l+3.
// ---------------------------------------------------------------------------
__global__ __launch_bounds__(256) void prep_kernel(const float* __restrict__ s1,
                                                   const float* __restrict__ s2,
                                                   float* __restrict__ nrm,
                                                   __hip_bfloat16* __restrict__ s1b,
                                                   __hip_bfloat16* __restrict__ s2b) {
    const int w = threadIdx.x >> 6, l = threadIdx.x & 63;
    const int base = (blockIdx.x << 4) + (w << 2);  // 16 rows/block, 4/wave
#pragma unroll
    for (int i = 0; i < 4; ++i) {
        const int row = base + i;          // 0 .. 32767
        const int second = row >> 14;      // rows >= 16384 are s2 (wave-uniform)
        const int r = row & 16383;
        const float* src = (second ? s2 : s1) + (size_t)r * D_DIM;
        __hip_bfloat16* dst = (second ? s2b : s1b) + (size_t)r * D_DIM;
        float4 v = reinterpret_cast<const float4*>(src)[l];
        float s = v.x * v.x + v.y * v.y + v.z * v.z + v.w * v.w;
        bf16x4 bv;
        bv[0] = (__bf16)v.x; bv[1] = (__bf16)v.y; bv[2] = (__bf16)v.z; bv[3] = (__bf16)v.w;
        *reinterpret_cast<bf16x4*>(dst + l * 4) = bv;
#pragma unroll
        for (int o = 32; o > 0; o >>= 1) s += __shfl_xor(s, o, 64);
        if (l == 0) nrm[row] = s;
    }
}

// ---------------------------------------------------------------------------
// Main GEMM: bf16 inputs, global_load_lds(16B) staging, XOR-swizzled LDS,
// 128x128 tile, BK=32, 4 waves, 16x16x32 bf16 MFMA.
// Counted-vmcnt 2-deep pipeline (T4): stage(kt+2) issued after all waves
// finish reading buf[cur]; main loop waits vmcnt(4), never drains to 0.
// Raw s_barrier (no implicit drain). Barriers are wave-uniform (kt-only
// conditions) -> no divergence race.
// epilogue out = 1/(1+sqrt(max(x2+y2-2xy,0))).
// ---------------------------------------------------------------------------
__global__ __launch_bounds__(256) void dist_gemm_bf16_kernel(const __hip_bfloat16* __restrict__ s1b,
                                                             const __hip_bfloat16* __restrict__ s2b,
                                                             const float* __restrict__ nrm,
                                                             float* __restrict__ out) {
    __shared__ __bf16 Alds[2][128 * 32];
    __shared__ __bf16 Blds[2][128 * 32];

    const int t = threadIdx.x;
    const int p = blockIdx.x;
    // XCD-aware swizzle: each XCD owns 128 consecutive logical tiles = 2 batches.
    const int d = ((p & 7) << 7) + (p >> 3);  // bijective for 1024 blocks
    const int batch = d >> 6;
    const int tile = d & 63;
    const int row0 = (tile >> 3) << 7;
    const int col0 = (tile & 7) << 7;

    const __hip_bfloat16* Ag = s1b + ((size_t)batch * L_DIM + row0) * D_DIM;
    const __hip_bfloat16* Bg = s2b + ((size_t)batch * L_DIM + col0) * D_DIM;

    const int l = t & 63, w = t >> 6;
    const int wr = w >> 1, wc = w & 1;   // wave -> 64x64 quadrant
    const int lr = l & 15;               // frag row (A) / col (B,C)
    const int lq = l >> 4;               // quarter = base 16B slot

    // staging geometry: wave w, call i covers segment s = w*2+i = rows s*16..+15.
    // lane l -> row s*16 + (l>>2); LDS dest linear (slot l&3);
    // global SOURCE slot pre-swizzled: (l&3) ^ ((l>>3)&3) = (l&3) ^ ((row>>1)&3).
    const int srow_in_seg = l >> 2;
    const int sslot = (l & 3) ^ ((l >> 3) & 3);

    f32x4 acc[4][4] = {};

    auto stage = [&](int buf, int kt) {
        const int k0 = kt << 5;
#pragma unroll
        for (int i = 0; i < 2; ++i) {
            const int s = (w << 1) | i;
            const int rl = (s << 4) + srow_in_seg;
            GLOAD_LDS16(Ag + rl * D_DIM + k0 + sslot * 8, &Alds[buf][s << 9]);
            GLOAD_LDS16(Bg + rl * D_DIM + k0 + sslot * 8, &Blds[buf][s << 9]);
        }
    };

    stage(0, 0);   // 4 loads
    stage(1, 1);   // 4 loads -> 8 outstanding
#pragma unroll
    for (int kt = 0; kt < 8; ++kt) {
        const int cur = kt & 1;
        // buf[cur]'s 4 loads are the oldest; allow the newest 4 to stay in flight.
        if (kt < 7) asm volatile("s_waitcnt vmcnt(4)" ::: "memory");
        else        asm volatile("s_waitcnt vmcnt(0)" ::: "memory");
        __builtin_amdgcn_s_barrier();            // all waves: buf[cur] staged

        bf16x8 aF[4], bF[4];
#pragma unroll
        for (int m = 0; m < 4; ++m) {
            const int row = (wr << 6) + (m << 4) + lr;
            const int sl = lq ^ ((row >> 1) & 3);
            aF[m] = *reinterpret_cast<const bf16x8*>(&Alds[cur][(row << 5) + (sl << 3)]);
        }
#pragma unroll
        for (int n = 0; n < 4; ++n) {
            const int row = (wc << 6) + (n << 4) + lr;
            const int sl = lq ^ ((row >> 1) & 3);
            bF[n] = *reinterpret_cast<const bf16x8*>(&Blds[cur][(row << 5) + (sl << 3)]);
        }
        asm volatile("s_waitcnt lgkmcnt(0)" ::: "memory");
        __builtin_amdgcn_sched_barrier(0);
        __builtin_amdgcn_s_barrier();            // all waves done reading buf[cur]
        if (kt < 6) stage(cur, kt + 2);          // safe to overwrite; loads fly over MFMA

#pragma unroll
        for (int m = 0; m < 4; ++m)
#pragma unroll
            for (int n = 0; n < 4; ++n)
                acc[m][n] = __builtin_amdgcn_mfma_f32_16x16x32_bf16(aF[m], bF[n], acc[m][n], 0, 0, 0);
    }

    // epilogue
    const float* x2 = nrm + batch * L_DIM;
    const float* y2 = nrm + B_DIM * L_DIM + batch * L_DIM;
    float* outb = out + (size_t)batch * L_DIM * L_DIM;
    const int rbase = row0 + (wr << 6) + (lq << 2);
    const int cbase = col0 + (wc << 6) + lr;
#pragma unroll
    for (int n = 0; n < 4; ++n) {
        const int col = cbase + (n << 4);
        const float y2v = y2[col];
#pragma unroll
        for (int m = 0; m < 4; ++m) {
            const int rowf = rbase + (m << 4);
#pragma unroll
            for (int r = 0; r < 4; ++r) {
                const int row = rowf + r;
                float sq = x2[row] + y2v - 2.0f * acc[m][n][r];
                sq = fmaxf(sq, 0.0f);
                outb[(size_t)row * L_DIM + col] = 1.0f / (1.0f + sqrtf(sq));
            }
        }
    }
}

// ---------------------------------------------------------------------------
// Fallback path (round-1 kernels) for the case ws_size < needed.
// ---------------------------------------------------------------------------
__global__ __launch_bounds__(256) void norms_kernel(const float* __restrict__ s1,
                                                    const float* __restrict__ s2,
                                                    float* __restrict__ nrm) {
    int w = threadIdx.x >> 6, l = threadIdx.x & 63;
    int row = (blockIdx.x << 2) + w;
    const float* src = (row < B_DIM * L_DIM)
                           ? (s1 + (size_t)row * D_DIM)
                           : (s2 + (size_t)(row - B_DIM * L_DIM) * D_DIM);
    float4 v = reinterpret_cast<const float4*>(src)[l];
    float s = v.x * v.x + v.y * v.y + v.z * v.z + v.w * v.w;
#pragma unroll
    for (int o = 32; o > 0; o >>= 1) s += __shfl_xor(s, o, 64);
    if (l == 0) nrm[row] = s;
}

__global__ __launch_bounds__(256) void dist_gemm_kernel(const float* __restrict__ s1,
                                                        const float* __restrict__ s2,
                                                        const float* __restrict__ nrm,
                                                        float* __restrict__ out) {
    __shared__ __bf16 Alds[2][128 * 32];
    __shared__ __bf16 Blds[2][128 * 32];

    const int t = threadIdx.x;
    const int p = blockIdx.x;
    const int d = ((p & 7) << 7) + (p >> 3);
    const int batch = d >> 6;
    const int tile = d & 63;
    const int row0 = (tile >> 3) << 7;
    const int col0 = (tile & 7) << 7;

    const float* Ag = s1 + ((size_t)batch * L_DIM + row0) * D_DIM;
    const float* Bg = s2 + ((size_t)batch * L_DIM + col0) * D_DIM;

    const int sr = t >> 2;
    const int sc = (t & 3) << 3;

    const int l = t & 63, w = t >> 6;
    const int wr = w >> 1, wc = w & 1;
    const int lr = l & 15;
    const int lk = (l >> 4) << 3;

    f32x4 acc[4][4] = {};

    auto stage = [&](int buf, int k0) {
#pragma unroll
        for (int pass = 0; pass < 2; ++pass) {
            const int r = sr + (pass << 6);
            const float4* sa = reinterpret_cast<const float4*>(Ag + (size_t)r * D_DIM + k0 + sc);
            float4 a0 = sa[0], a1 = sa[1];
            const float4* sb = reinterpret_cast<const float4*>(Bg + (size_t)r * D_DIM + k0 + sc);
            float4 b0 = sb[0], b1 = sb[1];
            bf16x8 av, bv;
            av[0] = (__bf16)a0.x; av[1] = (__bf16)a0.y; av[2] = (__bf16)a0.z; av[3] = (__bf16)a0.w;
            av[4] = (__bf16)a1.x; av[5] = (__bf16)a1.y; av[6] = (__bf16)a1.z; av[7] = (__bf16)a1.w;
            bv[0] = (__bf16)b0.x; bv[1] = (__bf16)b0.y; bv[2] = (__bf16)b0.z; bv[3] = (__bf16)b0.w;
            bv[4] = (__bf16)b1.x; bv[5] = (__bf16)b1.y; bv[6] = (__bf16)b1.z; bv[7] = (__bf16)b1.w;
            *reinterpret_cast<bf16x8*>(&Alds[buf][(r << 5) + sc]) = av;
            *reinterpret_cast<bf16x8*>(&Blds[buf][(r << 5) + sc]) = bv;
        }
    };

    stage(0, 0);
    __syncthreads();
    int cur = 0;
    for (int kt = 0; kt < 8; ++kt) {
        if (kt < 7) stage(cur ^ 1, (kt + 1) << 5);
        bf16x8 aF[4], bF[4];
#pragma unroll
        for (int m = 0; m < 4; ++m)
            aF[m] = *reinterpret_cast<const bf16x8*>(
                &Alds[cur][(((wr << 6) + (m << 4) + lr) << 5) + lk]);
#pragma unroll
        for (int n = 0; n < 4; ++n)
            bF[n] = *reinterpret_cast<const bf16x8*>(
                &Blds[cur][(((wc << 6) + (n << 4) + lr) << 5) + lk]);
#pragma unroll
        for (int m = 0; m < 4; ++m)
#pragma unroll
            for (int n = 0; n < 4; ++n)
                acc[m][n] = __builtin_amdgcn_mfma_f32_16x16x32_bf16(aF[m], bF[n], acc[m][n], 0, 0, 0);
        __syncthreads();
        cur ^= 1;
    }

    const float* x2 = nrm + batch * L_DIM;
    const float* y2 = nrm + B_DIM * L_DIM + batch * L_DIM;
    float* outb = out + (size_t)batch * L_DIM * L_DIM;
    const int rbase = row0 + (wr << 6) + ((l >> 4) << 2);
    const int cbase = col0 + (wc << 6) + lr;
#pragma unroll
    for (int n = 0; n < 4; ++n) {
        const int col = cbase + (n << 4);
        const float y2v = y2[col];
#pragma unroll
        for (int m = 0; m < 4; ++m) {
            const int rowf = rbase + (m << 4);
#pragma unroll
            for (int r = 0; r < 4; ++r) {
                const int row = rowf + r;
                float sq = x2[row] + y2v - 2.0f * acc[m][n][r];
                sq = fmaxf(sq, 0.0f);
                outb[(size_t)row * L_DIM + col] = 1.0f / (1.0f + sqrtf(sq));
            }
        }
    }
}

extern "C" void kernel_launch(void* const* d_in, const int* in_sizes, int n_in,
                              void* d_out, int out_size, void* d_ws, size_t ws_size,
                              hipStream_t stream) {
    (void)in_sizes; (void)n_in; (void)out_size;
    const float* s1 = (const float*)d_in[1];
    const float* s2 = (const float*)d_in[2];
    float* out = (float*)d_out;

    const size_t NRM_BYTES = 2u * B_DIM * L_DIM * sizeof(float);          // 128 KB
    const size_t BF_BYTES = (size_t)B_DIM * L_DIM * D_DIM * sizeof(__hip_bfloat16);  // 8 MB each
    const size_t NEED = NRM_BYTES + 2 * BF_BYTES;                          // ~16.9 MB

    float* nrm = (float*)d_ws;
    if (ws_size >= NEED) {
        __hip_bfloat16* s1b = (__hip_bfloat16*)((char*)d_ws + NRM_BYTES);
        __hip_bfloat16* s2b = (__hip_bfloat16*)((char*)d_ws + NRM_BYTES + BF_BYTES);
        prep_kernel<<<2048, 256, 0, stream>>>(s1, s2, nrm, s1b, s2b);
        dist_gemm_bf16_kernel<<<1024, 256, 0, stream>>>(s1b, s2b, nrm, out);
    } else {
        norms_kernel<<<8192, 256, 0, stream>>>(s1, s2, nrm);
        dist_gemm_kernel<<<1024, 256, 0, stream>>>(s1, s2, nrm, out);
    }
}

// Round 4
// 34.576 us; speedup vs baseline: 1.4231x; 1.1831x over previous
//
#include <hip/hip_runtime.h>
#include <hip/hip_bf16.h>

typedef __attribute__((ext_vector_type(4))) float f32x4;
typedef __attribute__((ext_vector_type(8))) __bf16 bf16x8;
typedef __attribute__((ext_vector_type(4))) __bf16 bf16x4;

#define B_DIM 16
#define L_DIM 1024
#define D_DIM 256

#define GLOAD_LDS16(g, lptr)                                          \
    __builtin_amdgcn_global_load_lds(                                 \
        (const __attribute__((address_space(1))) void*)(g),           \
        (__attribute__((address_space(3))) void*)(lptr), 16, 0, 0)

// ---------------------------------------------------------------------------
// Prep: row norms + fp32->bf16 conversion in one pass.
// ---------------------------------------------------------------------------
__global__ __launch_bounds__(256) void prep_kernel(const float* __restrict__ s1,
                                                   const float* __restrict__ s2,
                                                   float* __restrict__ nrm,
                                                   __hip_bfloat16* __restrict__ s1b,
                                                   __hip_bfloat16* __restrict__ s2b) {
    const int w = threadIdx.x >> 6, l = threadIdx.x & 63;
    const int base = (blockIdx.x << 4) + (w << 2);  // 16 rows/block, 4/wave
#pragma unroll
    for (int i = 0; i < 4; ++i) {
        const int row = base + i;          // 0 .. 32767
        const int second = row >> 14;      // rows >= 16384 are s2 (wave-uniform)
        const int r = row & 16383;
        const float* src = (second ? s2 : s1) + (size_t)r * D_DIM;
        __hip_bfloat16* dst = (second ? s2b : s1b) + (size_t)r * D_DIM;
        float4 v = reinterpret_cast<const float4*>(src)[l];
        float s = v.x * v.x + v.y * v.y + v.z * v.z + v.w * v.w;
        bf16x4 bv;
        bv[0] = (__bf16)v.x; bv[1] = (__bf16)v.y; bv[2] = (__bf16)v.z; bv[3] = (__bf16)v.w;
        *reinterpret_cast<bf16x4*>(dst + l * 4) = bv;
#pragma unroll
        for (int o = 32; o > 0; o >>= 1) s += __shfl_xor(s, o, 64);
        if (l == 0) nrm[row] = s;
    }
}

// ---------------------------------------------------------------------------
// Main GEMM, register-pipelined schedule:
//   4 LDS buffers (64KB), stage(kt+3) issued at step kt -> needed buffer is
//   always oldest in flight -> counted vmcnt(4); ONE barrier per step.
//   Frags(kt+1) ds_read'd during step kt; frags(kt) drained with lgkmcnt(8);
//   MFMAs(kt) overlap next step's reads and in-flight stages.
// Per-step safety (steady state, all waves at same kt due to barrier):
//   - C@kt reads buf[(kt+1)&3], staged by stage(kt+1): my vmcnt(4)@A drains
//     stage(kt+1) (oldest pending of {kt+1, kt+2}); barrier B makes it global.
//   - F@kt overwrites buf[(kt+3)&3] = buf[(kt-1)&3], last read as frags(kt-1)
//     (issued C@kt-2, drained D@kt-1 by lgkmcnt(8)); barrier B@kt orders all
//     waves' D@kt-1 before any wave's F@kt.
// ---------------------------------------------------------------------------
__global__ __launch_bounds__(256) void dist_gemm_bf16_kernel(const __hip_bfloat16* __restrict__ s1b,
                                                             const __hip_bfloat16* __restrict__ s2b,
                                                             const float* __restrict__ nrm,
                                                             float* __restrict__ out) {
    __shared__ __bf16 Alds[4][128 * 32];
    __shared__ __bf16 Blds[4][128 * 32];

    const int t = threadIdx.x;
    const int p = blockIdx.x;
    // XCD-aware swizzle: each XCD owns 128 consecutive logical tiles = 2 batches.
    const int d = ((p & 7) << 7) + (p >> 3);  // bijective for 1024 blocks
    const int batch = d >> 6;
    const int tile = d & 63;
    const int row0 = (tile >> 3) << 7;
    const int col0 = (tile & 7) << 7;

    const __hip_bfloat16* Ag = s1b + ((size_t)batch * L_DIM + row0) * D_DIM;
    const __hip_bfloat16* Bg = s2b + ((size_t)batch * L_DIM + col0) * D_DIM;

    const int l = t & 63, w = t >> 6;
    const int wr = w >> 1, wc = w & 1;   // wave -> 64x64 quadrant
    const int lr = l & 15;               // frag row (A) / col (B,C)
    const int lq = l >> 4;               // quarter = base 16B slot

    // staging: wave w, call i covers segment s = w*2+i = rows s*16..+15.
    // LDS dest linear; global SOURCE slot pre-swizzled (l&3)^((row>>1)&3).
    const int srow_in_seg = l >> 2;
    const int sslot = (l & 3) ^ ((l >> 3) & 3);

    f32x4 acc[4][4] = {};

    auto stageK = [&](int kt) {          // 4 gload_lds, writes buf kt&3
        const int k0 = kt << 5;
        const int b = kt & 3;
#pragma unroll
        for (int i = 0; i < 2; ++i) {
            const int s = (w << 1) | i;
            const int rl = (s << 4) + srow_in_seg;
            GLOAD_LDS16(Ag + rl * D_DIM + k0 + sslot * 8, &Alds[b][s << 9]);
            GLOAD_LDS16(Bg + rl * D_DIM + k0 + sslot * 8, &Blds[b][s << 9]);
        }
    };

    auto readFrags = [&](int kt, bf16x8* aF, bf16x8* bF) {  // 8 ds_read_b128
        const int b = kt & 3;
#pragma unroll
        for (int m = 0; m < 4; ++m) {
            const int row = (wr << 6) + (m << 4) + lr;
            const int sl = lq ^ ((row >> 1) & 3);
            aF[m] = *reinterpret_cast<const bf16x8*>(&Alds[b][(row << 5) + (sl << 3)]);
        }
#pragma unroll
        for (int n = 0; n < 4; ++n) {
            const int row = (wc << 6) + (n << 4) + lr;
            const int sl = lq ^ ((row >> 1) & 3);
            bF[n] = *reinterpret_cast<const bf16x8*>(&Blds[b][(row << 5) + (sl << 3)]);
        }
    };

    bf16x8 aF[2][4], bF[2][4];

    // Prologue: 3 stages in flight; drain stage0+stage1 (C@0 reads frags(1)).
    stageK(0); stageK(1); stageK(2);                     // 12 loads
    asm volatile("s_waitcnt vmcnt(4)" ::: "memory");     // stage0, stage1 landed
    __builtin_amdgcn_s_barrier();
    readFrags(0, aF[0], bF[0]);

#pragma unroll
    for (int kt = 0; kt < 8; ++kt) {
        if (kt >= 1) {
            // pending: stage(kt+1) [oldest] + stage(kt+2); drain oldest.
            if (kt <= 5) asm volatile("s_waitcnt vmcnt(4)" ::: "memory");
            else         asm volatile("s_waitcnt vmcnt(0)" ::: "memory");
            __builtin_amdgcn_s_barrier();
        }
        if (kt < 7) readFrags(kt + 1, aF[(kt + 1) & 1], bF[(kt + 1) & 1]);
        // drain frags(kt) (oldest 8 lgkm ops), keep frags(kt+1) in flight
        if (kt < 7) asm volatile("s_waitcnt lgkmcnt(8)" ::: "memory");
        else        asm volatile("s_waitcnt lgkmcnt(0)" ::: "memory");
        if (kt <= 4) stageK(kt + 3);

        __builtin_amdgcn_s_setprio(1);
#pragma unroll
        for (int m = 0; m < 4; ++m)
#pragma unroll
            for (int n = 0; n < 4; ++n)
                acc[m][n] = __builtin_amdgcn_mfma_f32_16x16x32_bf16(
                    aF[kt & 1][m], bF[kt & 1][n], acc[m][n], 0, 0, 0);
        __builtin_amdgcn_s_setprio(0);
    }

    // epilogue
    const float* x2 = nrm + batch * L_DIM;
    const float* y2 = nrm + B_DIM * L_DIM + batch * L_DIM;
    float* outb = out + (size_t)batch * L_DIM * L_DIM;
    const int rbase = row0 + (wr << 6) + (lq << 2);
    const int cbase = col0 + (wc << 6) + lr;
#pragma unroll
    for (int n = 0; n < 4; ++n) {
        const int col = cbase + (n << 4);
        const float y2v = y2[col];
#pragma unroll
        for (int m = 0; m < 4; ++m) {
            const int rowf = rbase + (m << 4);
#pragma unroll
            for (int r = 0; r < 4; ++r) {
                const int row = rowf + r;
                float sq = x2[row] + y2v - 2.0f * acc[m][n][r];
                sq = fmaxf(sq, 0.0f);
                float den = 1.0f + __builtin_amdgcn_sqrtf(sq);
                outb[(size_t)row * L_DIM + col] = __builtin_amdgcn_rcpf(den);
            }
        }
    }
}

// ---------------------------------------------------------------------------
// Fallback path (round-1 kernels) for the case ws_size < needed.
// ---------------------------------------------------------------------------
__global__ __launch_bounds__(256) void norms_kernel(const float* __restrict__ s1,
                                                    const float* __restrict__ s2,
                                                    float* __restrict__ nrm) {
    int w = threadIdx.x >> 6, l = threadIdx.x & 63;
    int row = (blockIdx.x << 2) + w;
    const float* src = (row < B_DIM * L_DIM)
                           ? (s1 + (size_t)row * D_DIM)
                           : (s2 + (size_t)(row - B_DIM * L_DIM) * D_DIM);
    float4 v = reinterpret_cast<const float4*>(src)[l];
    float s = v.x * v.x + v.y * v.y + v.z * v.z + v.w * v.w;
#pragma unroll
    for (int o = 32; o > 0; o >>= 1) s += __shfl_xor(s, o, 64);
    if (l == 0) nrm[row] = s;
}

__global__ __launch_bounds__(256) void dist_gemm_kernel(const float* __restrict__ s1,
                                                        const float* __restrict__ s2,
                                                        const float* __restrict__ nrm,
                                                        float* __restrict__ out) {
    __shared__ __bf16 Alds[2][128 * 32];
    __shared__ __bf16 Blds[2][128 * 32];

    const int t = threadIdx.x;
    const int p = blockIdx.x;
    const int d = ((p & 7) << 7) + (p >> 3);
    const int batch = d >> 6;
    const int tile = d & 63;
    const int row0 = (tile >> 3) << 7;
    const int col0 = (tile & 7) << 7;

    const float* Ag = s1 + ((size_t)batch * L_DIM + row0) * D_DIM;
    const float* Bg = s2 + ((size_t)batch * L_DIM + col0) * D_DIM;

    const int sr = t >> 2;
    const int sc = (t & 3) << 3;

    const int l = t & 63, w = t >> 6;
    const int wr = w >> 1, wc = w & 1;
    const int lr = l & 15;
    const int lk = (l >> 4) << 3;

    f32x4 acc[4][4] = {};

    auto stage = [&](int buf, int k0) {
#pragma unroll
        for (int pass = 0; pass < 2; ++pass) {
            const int r = sr + (pass << 6);
            const float4* sa = reinterpret_cast<const float4*>(Ag + (size_t)r * D_DIM + k0 + sc);
            float4 a0 = sa[0], a1 = sa[1];
            const float4* sb = reinterpret_cast<const float4*>(Bg + (size_t)r * D_DIM + k0 + sc);
            float4 b0 = sb[0], b1 = sb[1];
            bf16x8 av, bv;
            av[0] = (__bf16)a0.x; av[1] = (__bf16)a0.y; av[2] = (__bf16)a0.z; av[3] = (__bf16)a0.w;
            av[4] = (__bf16)a1.x; av[5] = (__bf16)a1.y; av[6] = (__bf16)a1.z; av[7] = (__bf16)a1.w;
            bv[0] = (__bf16)b0.x; bv[1] = (__bf16)b0.y; bv[2] = (__bf16)b0.z; bv[3] = (__bf16)b0.w;
            bv[4] = (__bf16)b1.x; bv[5] = (__bf16)b1.y; bv[6] = (__bf16)b1.z; bv[7] = (__bf16)b1.w;
            *reinterpret_cast<bf16x8*>(&Alds[buf][(r << 5) + sc]) = av;
            *reinterpret_cast<bf16x8*>(&Blds[buf][(r << 5) + sc]) = bv;
        }
    };

    stage(0, 0);
    __syncthreads();
    int cur = 0;
    for (int kt = 0; kt < 8; ++kt) {
        if (kt < 7) stage(cur ^ 1, (kt + 1) << 5);
        bf16x8 aF[4], bF[4];
#pragma unroll
        for (int m = 0; m < 4; ++m)
            aF[m] = *reinterpret_cast<const bf16x8*>(
                &Alds[cur][(((wr << 6) + (m << 4) + lr) << 5) + lk]);
#pragma unroll
        for (int n = 0; n < 4; ++n)
            bF[n] = *reinterpret_cast<const bf16x8*>(
                &Blds[cur][(((wc << 6) + (n << 4) + lr) << 5) + lk]);
#pragma unroll
        for (int m = 0; m < 4; ++m)
#pragma unroll
            for (int n = 0; n < 4; ++n)
                acc[m][n] = __builtin_amdgcn_mfma_f32_16x16x32_bf16(aF[m], bF[n], acc[m][n], 0, 0, 0);
        __syncthreads();
        cur ^= 1;
    }

    const float* x2 = nrm + batch * L_DIM;
    const float* y2 = nrm + B_DIM * L_DIM + batch * L_DIM;
    float* outb = out + (size_t)batch * L_DIM * L_DIM;
    const int rbase = row0 + (wr << 6) + ((l >> 4) << 2);
    const int cbase = col0 + (wc << 6) + lr;
#pragma unroll
    for (int n = 0; n < 4; ++n) {
        const int col = cbase + (n << 4);
        const float y2v = y2[col];
#pragma unroll
        for (int m = 0; m < 4; ++m) {
            const int rowf = rbase + (m << 4);
#pragma unroll
            for (int r = 0; r < 4; ++r) {
                const int row = rowf + r;
                float sq = x2[row] + y2v - 2.0f * acc[m][n][r];
                sq = fmaxf(sq, 0.0f);
                outb[(size_t)row * L_DIM + col] = 1.0f / (1.0f + sqrtf(sq));
            }
        }
    }
}

extern "C" void kernel_launch(void* const* d_in, const int* in_sizes, int n_in,
                              void* d_out, int out_size, void* d_ws, size_t ws_size,
                              hipStream_t stream) {
    (void)in_sizes; (void)n_in; (void)out_size;
    const float* s1 = (const float*)d_in[1];
    const float* s2 = (const float*)d_in[2];
    float* out = (float*)d_out;

    const size_t NRM_BYTES = 2u * B_DIM * L_DIM * sizeof(float);          // 128 KB
    const size_t BF_BYTES = (size_t)B_DIM * L_DIM * D_DIM * sizeof(__hip_bfloat16);  // 8 MB each
    const size_t NEED = NRM_BYTES + 2 * BF_BYTES;                          // ~16.9 MB

    float* nrm = (float*)d_ws;
    if (ws_size >= NEED) {
        __hip_bfloat16* s1b = (__hip_bfloat16*)((char*)d_ws + NRM_BYTES);
        __hip_bfloat16* s2b = (__hip_bfloat16*)((char*)d_ws + NRM_BYTES + BF_BYTES);
        prep_kernel<<<2048, 256, 0, stream>>>(s1, s2, nrm, s1b, s2b);
        dist_gemm_bf16_kernel<<<1024, 256, 0, stream>>>(s1b, s2b, nrm, out);
    } else {
        norms_kernel<<<8192, 256, 0, stream>>>(s1, s2, nrm);
        dist_gemm_kernel<<<1024, 256, 0, stream>>>(s1, s2, nrm, out);
    }
}